// Round 10
// baseline (2466.668 us; speedup 1.0000x reference)
//
#include <hip/hip_runtime.h>

#define EMBED 32
#define HIDDEN 64
#define NCLS 10
#define C1 128   // nodes per block, layer-1 gather (seg = 16 KB)
#define C2 128   // nodes per block, layer-2 gather (seg = 32 KB)

// ============ CSR construction ============

__global__ void deg_kernel(const int* __restrict__ dst, int* __restrict__ deg, int nEdges) {
    int e = blockIdx.x * blockDim.x + threadIdx.x;
    if (e >= nEdges) return;
    atomicAdd(&deg[dst[e]], 1);
}

__global__ void block_sum_kernel(const int* __restrict__ deg, int* __restrict__ blockSums, int n) {
    __shared__ int s[256];
    int i = blockIdx.x * 256 + threadIdx.x;
    s[threadIdx.x] = (i < n) ? deg[i] : 0;
    __syncthreads();
    for (int off = 128; off > 0; off >>= 1) {
        if (threadIdx.x < off) s[threadIdx.x] += s[threadIdx.x + off];
        __syncthreads();
    }
    if (threadIdx.x == 0) blockSums[blockIdx.x] = s[0];
}

__global__ void scan_sums_kernel(int* blockSums, int nb) {
    if (blockIdx.x == 0 && threadIdx.x == 0) {
        int acc = 0;
        for (int i = 0; i < nb; ++i) { int v = blockSums[i]; blockSums[i] = acc; acc += v; }
    }
}

__global__ void scan_local_kernel(const int* __restrict__ deg, const int* __restrict__ blockSums,
                                  int* __restrict__ rowptr, int n) {
    __shared__ int s[256];
    int i = blockIdx.x * 256 + threadIdx.x;
    int v = (i < n) ? deg[i] : 0;
    s[threadIdx.x] = v;
    __syncthreads();
    for (int off = 1; off < 256; off <<= 1) {
        int t = (threadIdx.x >= off) ? s[threadIdx.x - off] : 0;
        __syncthreads();
        s[threadIdx.x] += t;
        __syncthreads();
    }
    if (i < n) rowptr[i] = blockSums[blockIdx.x] + s[threadIdx.x] - v;  // exclusive
}

__global__ void fill_kernel(const int* __restrict__ src, const int* __restrict__ dst,
                            const int* __restrict__ rowptr, int* __restrict__ cursor,
                            int* __restrict__ nbr, int* __restrict__ edst, int nEdges) {
    int e = blockIdx.x * blockDim.x + threadIdx.x;
    if (e >= nEdges) return;
    int d = dst[e];
    int pos = atomicAdd(&cursor[d], 1);
    int at = rowptr[d] + pos;
    nbr[at] = src[e];
    if (edst) edst[at] = d;
}

// gcnt[g] = #nodes with batch==g, via binary search (batch is sorted)
__global__ void gcnt_kernel(const int* __restrict__ batch, float* __restrict__ gcnt,
                            int nNodes, int nGraphs) {
    int g = blockIdx.x * blockDim.x + threadIdx.x;
    if (g >= nGraphs) return;
    int lo = 0, hi = nNodes;
    while (lo < hi) { int m = (lo + hi) >> 1; if (batch[m] < g) lo = m + 1; else hi = m; }
    int lo2 = lo, hi2 = nNodes;
    while (lo2 < hi2) { int m = (lo2 + hi2) >> 1; if (batch[m] <= g) lo2 = m + 1; else hi2 = m; }
    gcnt[g] = (float)(lo2 - lo);
}

// ============ Layer-1 gather: edge-parallel, LDS segment accumulate ============
__launch_bounds__(512)
__global__ void gather1_lds(const int* __restrict__ nbr, const int* __restrict__ edst,
                            const int* __restrict__ rowptr, const int* __restrict__ deg,
                            const int* __restrict__ node_ids, const float* __restrict__ embed,
                            float* __restrict__ agg1, int nNodes, int nEdges) {
    __shared__ float seg[C1 * EMBED];   // 16 KB
    int tid = threadIdx.x, wave = tid >> 6, lane = tid & 63;
    int half = lane >> 5, f = lane & 31;
    int n0 = blockIdx.x * C1;
    int nEnd = min(n0 + C1, nNodes);
    int estart = rowptr[n0];
    int eend = (nEnd < nNodes) ? rowptr[nEnd] : nEdges;

    for (int i = tid; i < C1 * EMBED; i += 512) seg[i] = 0.f;
    __syncthreads();

    // 16 edge slots (8 waves x 2 halves), stride 16, unroll 4
    int e = estart + wave * 2 + half;
    for (; e + 48 < eend; e += 64) {
        #pragma unroll
        for (int u = 0; u < 4; ++u) {
            int ee = e + u * 16;
            int ln = edst[ee] - n0;
            int s  = nbr[ee];
            float v = embed[(size_t)node_ids[s] * EMBED + f];
            atomicAdd(&seg[ln * EMBED + f], v);
        }
    }
    for (; e < eend; e += 16) {
        int ln = edst[e] - n0;
        int s  = nbr[e];
        float v = embed[(size_t)node_ids[s] * EMBED + f];
        atomicAdd(&seg[ln * EMBED + f], v);
    }
    __syncthreads();

    for (int i = tid; i < (nEnd - n0) * EMBED; i += 512) {
        int n = n0 + (i >> 5);
        float dv = fmaxf((float)deg[n], 1.f);
        agg1[(size_t)n0 * EMBED + i] = seg[i] / dv;
    }
}

// ============ Layer-1 update: h1 = relu(agg1@W1l + b1 + x@W1r), 2 nodes/wave ============
__launch_bounds__(512)
__global__ void update1_kernel(const float* __restrict__ agg1, const int* __restrict__ node_ids,
                               const float* __restrict__ embed,
                               const float* __restrict__ W1l, const float* __restrict__ b1,
                               const float* __restrict__ W1r, float* __restrict__ h1, int nNodes) {
    __shared__ float sW[EMBED * 2 * HIDDEN];   // 16 KB, (Wl,Wr) interleaved
    int tid = threadIdx.x;
    for (int i = tid; i < EMBED * HIDDEN; i += 512) {
        int k = i >> 6, c = i & 63;
        sW[k * 128 + 2 * c]     = W1l[i];
        sW[k * 128 + 2 * c + 1] = W1r[i];
    }
    __syncthreads();

    int wave = tid >> 6, lane = tid & 63;
    float bias = b1[lane];
    int wid = blockIdx.x * 8 + wave, stride = gridDim.x * 8;
    int nPairs = (nNodes + 1) >> 1;
    for (int p = wid; p < nPairs; p += stride) {
        int n0 = 2 * p, n1 = 2 * p + 1;
        bool has1 = (n1 < nNodes);
        float av0 = (lane < EMBED) ? agg1[(size_t)n0 * EMBED + lane]
                                   : embed[(size_t)node_ids[n0] * EMBED + (lane - EMBED)];
        float av1 = has1 ? ((lane < EMBED) ? agg1[(size_t)n1 * EMBED + lane]
                                           : embed[(size_t)node_ids[n1] * EMBED + (lane - EMBED)])
                         : 0.f;
        float acc0 = bias, acc1 = bias;
        #pragma unroll
        for (int k = 0; k < EMBED; ++k) {
            float2 w = *(const float2*)&sW[k * 128 + 2 * lane];
            acc0 += __shfl(av0, k) * w.x + __shfl(av0, EMBED + k) * w.y;
            acc1 += __shfl(av1, k) * w.x + __shfl(av1, EMBED + k) * w.y;
        }
        h1[(size_t)n0 * HIDDEN + lane] = fmaxf(acc0, 0.f);
        if (has1) h1[(size_t)n1 * HIDDEN + lane] = fmaxf(acc1, 0.f);
    }
}

// ============ Layer-2 gather: edge-parallel, LDS segment accumulate ============
__launch_bounds__(512)
__global__ void gather2_lds(const int* __restrict__ nbr, const int* __restrict__ edst,
                            const int* __restrict__ rowptr, const int* __restrict__ deg,
                            const float* __restrict__ h1, float* __restrict__ agg2,
                            int nNodes, int nEdges) {
    __shared__ float seg[C2 * HIDDEN];  // 32 KB
    int tid = threadIdx.x, wave = tid >> 6, lane = tid & 63;
    int n0 = blockIdx.x * C2;
    int nEnd = min(n0 + C2, nNodes);
    int estart = rowptr[n0];
    int eend = (nEnd < nNodes) ? rowptr[nEnd] : nEdges;

    for (int i = tid; i < C2 * HIDDEN; i += 512) seg[i] = 0.f;
    __syncthreads();

    // 8 edge slots (one per wave), stride 8, unroll 4
    int e = estart + wave;
    for (; e + 24 < eend; e += 32) {
        #pragma unroll
        for (int u = 0; u < 4; ++u) {
            int ee = e + u * 8;
            int ln = edst[ee] - n0;
            int s  = nbr[ee];
            float v = h1[(size_t)s * HIDDEN + lane];   // coalesced 256 B row
            atomicAdd(&seg[ln * HIDDEN + lane], v);
        }
    }
    for (; e < eend; e += 8) {
        int ln = edst[e] - n0;
        int s  = nbr[e];
        float v = h1[(size_t)s * HIDDEN + lane];
        atomicAdd(&seg[ln * HIDDEN + lane], v);
    }
    __syncthreads();

    for (int i = tid; i < (nEnd - n0) * HIDDEN; i += 512) {
        int n = n0 + (i >> 6);
        float dv = fmaxf((float)deg[n], 1.f);
        agg2[(size_t)n0 * HIDDEN + i] = seg[i] / dv;
    }
}

// ============ Layer-2 update + pool: contiguous ranges, run-flush pooling ============
__launch_bounds__(512)
__global__ void update2_kernel(const float* __restrict__ agg2, const float* __restrict__ h1,
                               const float* __restrict__ W2l, const float* __restrict__ b2,
                               const float* __restrict__ W2r, const int* __restrict__ batch,
                               float* __restrict__ pooled, int nNodes, int npw) {
    __shared__ float sW[HIDDEN * 2 * HIDDEN];  // 32 KB
    int tid = threadIdx.x;
    for (int i = tid; i < HIDDEN * HIDDEN; i += 512) {
        int k = i >> 6, c = i & 63;
        sW[k * 128 + 2 * c]     = W2l[i];
        sW[k * 128 + 2 * c + 1] = W2r[i];
    }
    __syncthreads();

    int wave = tid >> 6, lane = tid & 63;
    float bias = b2[lane];
    int w = blockIdx.x * 8 + wave;
    int nStart = w * npw;
    if (nStart >= nNodes) return;
    int nEnd = min(nStart + npw, nNodes);

    float pacc = 0.f;
    int gcur = batch[nStart];           // uniform across lanes
    for (int n = nStart; n < nEnd; n += 2) {
        int n1 = n + 1;
        bool has1 = (n1 < nEnd);
        float ag0 = agg2[(size_t)n * HIDDEN + lane];
        float xv0 = h1[(size_t)n * HIDDEN + lane];
        float ag1 = has1 ? agg2[(size_t)n1 * HIDDEN + lane] : 0.f;
        float xv1 = has1 ? h1[(size_t)n1 * HIDDEN + lane] : 0.f;
        float acc0 = bias, acc1 = bias;
        #pragma unroll
        for (int k = 0; k < HIDDEN; ++k) {
            float2 wv = *(const float2*)&sW[k * 128 + 2 * lane];
            acc0 += __shfl(ag0, k) * wv.x + __shfl(xv0, k) * wv.y;
            acc1 += __shfl(ag1, k) * wv.x + __shfl(xv1, k) * wv.y;
        }
        acc0 = fmaxf(acc0, 0.f);
        int g0 = batch[n];
        if (g0 != gcur) {
            atomicAdd(&pooled[(size_t)gcur * HIDDEN + lane], pacc);
            pacc = 0.f; gcur = g0;
        }
        pacc += acc0;
        if (has1) {
            float a1 = fmaxf(acc1, 0.f);
            int g1 = batch[n1];
            if (g1 != gcur) {
                atomicAdd(&pooled[(size_t)gcur * HIDDEN + lane], pacc);
                pacc = 0.f; gcur = g1;
            }
            pacc += a1;
        }
    }
    atomicAdd(&pooled[(size_t)gcur * HIDDEN + lane], pacc);
}

// ============ FALLBACK (round-6 fused, proven) ============

__launch_bounds__(512)
__global__ void layer1_fused(const int* __restrict__ nbr, const int* __restrict__ rowptr,
                             const int* __restrict__ deg, const int* __restrict__ node_ids,
                             const float* __restrict__ embed,
                             const float* __restrict__ W1l, const float* __restrict__ b1,
                             const float* __restrict__ W1r, float* __restrict__ h1, int nNodes) {
    __shared__ float sWl[EMBED * HIDDEN];
    __shared__ float sWr[EMBED * HIDDEN];
    int tid = threadIdx.x;
    for (int i = tid; i < EMBED * HIDDEN; i += 512) { sWl[i] = W1l[i]; sWr[i] = W1r[i]; }
    __syncthreads();
    int wave = tid >> 6, lane = tid & 63;
    int half = lane >> 5, f = lane & 31;
    float bias = b1[lane];
    for (int n = blockIdx.x * 8 + wave; n < nNodes; n += gridDim.x * 8) {
        int dg = deg[n], start = rowptr[n];
        float xv = embed[(size_t)node_ids[n] * EMBED + f];
        float s0 = 0.f, s1 = 0.f;
        int j = half;
        for (; j + 2 < dg; j += 4) {
            int n0 = nbr[start + j];
            int n1 = nbr[start + j + 2];
            s0 += embed[(size_t)node_ids[n0] * EMBED + f];
            s1 += embed[(size_t)node_ids[n1] * EMBED + f];
        }
        for (; j < dg; j += 2)
            s0 += embed[(size_t)node_ids[nbr[start + j]] * EMBED + f];
        float sum = s0 + s1;
        sum += __shfl_xor(sum, 32);
        float aggv = sum / fmaxf((float)dg, 1.f);
        float acc = bias;
        #pragma unroll
        for (int k = 0; k < EMBED; ++k) {
            float a = __shfl(aggv, k);
            float x = __shfl(xv, k);
            acc += a * sWl[k * HIDDEN + lane] + x * sWr[k * HIDDEN + lane];
        }
        h1[(size_t)n * HIDDEN + lane] = fmaxf(acc, 0.f);
    }
}

__launch_bounds__(512)
__global__ void layer2_fused(const int* __restrict__ nbr, const int* __restrict__ rowptr,
                             const int* __restrict__ deg, const float* __restrict__ h1,
                             const float* __restrict__ W2l, const float* __restrict__ b2,
                             const float* __restrict__ W2r, const int* __restrict__ batch,
                             float* __restrict__ pooled, float* __restrict__ gcnt, int nNodes) {
    __shared__ float sWl[HIDDEN * HIDDEN];
    __shared__ float sWr[HIDDEN * HIDDEN];
    int tid = threadIdx.x;
    for (int i = tid; i < HIDDEN * HIDDEN; i += 512) { sWl[i] = W2l[i]; sWr[i] = W2r[i]; }
    __syncthreads();
    int wave = tid >> 6, lane = tid & 63;
    float bias = b2[lane];
    for (int n = blockIdx.x * 8 + wave; n < nNodes; n += gridDim.x * 8) {
        int dg = deg[n], start = rowptr[n];
        int g = batch[n];
        float xv = h1[(size_t)n * HIDDEN + lane];
        float s0 = 0.f, s1 = 0.f, s2 = 0.f, s3 = 0.f;
        int j = 0;
        for (; j + 3 < dg; j += 4) {
            int n0 = nbr[start + j];
            int n1 = nbr[start + j + 1];
            int n2 = nbr[start + j + 2];
            int n3 = nbr[start + j + 3];
            s0 += h1[(size_t)n0 * HIDDEN + lane];
            s1 += h1[(size_t)n1 * HIDDEN + lane];
            s2 += h1[(size_t)n2 * HIDDEN + lane];
            s3 += h1[(size_t)n3 * HIDDEN + lane];
        }
        for (; j < dg; ++j)
            s0 += h1[(size_t)nbr[start + j] * HIDDEN + lane];
        float aggv = ((s0 + s1) + (s2 + s3)) / fmaxf((float)dg, 1.f);
        float acc = bias;
        #pragma unroll
        for (int k = 0; k < HIDDEN; ++k) {
            float a = __shfl(aggv, k);
            float x = __shfl(xv, k);
            acc += a * sWl[k * HIDDEN + lane] + x * sWr[k * HIDDEN + lane];
        }
        acc = fmaxf(acc, 0.f);
        atomicAdd(&pooled[(size_t)g * HIDDEN + lane], acc);
        if (lane == 0) atomicAdd(&gcnt[g], 1.f);
    }
}

// ============ classifier ============
__global__ void out_kernel(const float* __restrict__ pooled, const float* __restrict__ gcnt,
                           const float* __restrict__ Wout, const float* __restrict__ bout,
                           float* __restrict__ out, int nGraphs) {
    int i = blockIdx.x * blockDim.x + threadIdx.x;
    if (i >= nGraphs * NCLS) return;
    int g = i / NCLS;
    int c = i % NCLS;
    float inv = 1.0f / fmaxf(gcnt[g], 1.0f);
    float acc = bout[c];
    #pragma unroll
    for (int k = 0; k < HIDDEN; ++k)
        acc += pooled[(size_t)g * HIDDEN + k] * inv * Wout[k * NCLS + c];
    out[i] = acc;
}

extern "C" void kernel_launch(void* const* d_in, const int* in_sizes, int n_in,
                              void* d_out, int out_size, void* d_ws, size_t ws_size,
                              hipStream_t stream) {
    const int*   node_ids = (const int*)d_in[0];
    const int*   src      = (const int*)d_in[1];
    const int*   dst      = (const int*)d_in[2];
    const int*   batch    = (const int*)d_in[3];
    const float* embed    = (const float*)d_in[4];
    const float* W1l      = (const float*)d_in[5];
    const float* b1       = (const float*)d_in[6];
    const float* W1r      = (const float*)d_in[7];
    const float* W2l      = (const float*)d_in[8];
    const float* b2       = (const float*)d_in[9];
    const float* W2r      = (const float*)d_in[10];
    const float* Wout     = (const float*)d_in[11];
    const float* bout     = (const float*)d_in[12];

    const int N = in_sizes[0];          // 100000
    const int E = in_sizes[1];          // 1200000
    const int G = out_size / NCLS;      // 1024
    const int NB = (N + 255) / 256;

    // ws: deg[N] | rowptr[N] | cursor[N] | blockSums(pad) | nbr(padE) | edst(padE) (ints)
    //     h1[N*64] | pooled[G*64] | gcnt[padG] | agg[N*64] (floats)
    int* deg       = (int*)d_ws;
    int* rowptr    = deg + N;
    int* cursor    = rowptr + N;
    int* blockSums = cursor + N;
    int* nbr       = blockSums + ((NB + 63) & ~63);
    int* edst      = nbr + ((E + 63) & ~63);
    float* h1      = (float*)(edst + ((E + 63) & ~63));
    float* pooled  = h1 + (size_t)N * HIDDEN;
    float* gcnt    = pooled + (size_t)G * HIDDEN;
    float* agg     = gcnt + ((G + 63) & ~63);         // FIX: full G floats for gcnt (was +64)

    size_t need_split = ((char*)(agg + (size_t)N * HIDDEN)) - (char*)d_ws;
    const bool use_split = (ws_size >= need_split);   // constant across calls -> graph-safe

    float* out = (float*)d_out;

    // ---- CSR build ----
    hipMemsetAsync(deg, 0, (size_t)N * sizeof(int), stream);
    hipMemsetAsync(cursor, 0, (size_t)N * sizeof(int), stream);
    deg_kernel<<<(E + 255) / 256, 256, 0, stream>>>(dst, deg, E);
    block_sum_kernel<<<NB, 256, 0, stream>>>(deg, blockSums, N);
    scan_sums_kernel<<<1, 1, 0, stream>>>(blockSums, NB);
    scan_local_kernel<<<NB, 256, 0, stream>>>(deg, blockSums, rowptr, N);
    fill_kernel<<<(E + 255) / 256, 256, 0, stream>>>(src, dst, rowptr, cursor, nbr,
                                                     use_split ? edst : (int*)nullptr, E);

    hipMemsetAsync(pooled, 0, (size_t)G * HIDDEN * sizeof(float), stream);

    if (use_split) {
        gcnt_kernel<<<(G + 255) / 256, 256, 0, stream>>>(batch, gcnt, N, G);
        gather1_lds<<<(N + C1 - 1) / C1, 512, 0, stream>>>(nbr, edst, rowptr, deg, node_ids,
                                                           embed, agg, N, E);
        update1_kernel<<<1024, 512, 0, stream>>>(agg, node_ids, embed, W1l, b1, W1r, h1, N);
        gather2_lds<<<(N + C2 - 1) / C2, 512, 0, stream>>>(nbr, edst, rowptr, deg, h1, agg, N, E);
        int nWaves = 1024 * 8;
        int npw = (N + nWaves - 1) / nWaves;
        update2_kernel<<<1024, 512, 0, stream>>>(agg, h1, W2l, b2, W2r, batch, pooled, N, npw);
    } else {
        hipMemsetAsync(gcnt, 0, (size_t)G * sizeof(float), stream);
        layer1_fused<<<1024, 512, 0, stream>>>(nbr, rowptr, deg, node_ids, embed,
                                               W1l, b1, W1r, h1, N);
        layer2_fused<<<1024, 512, 0, stream>>>(nbr, rowptr, deg, h1, W2l, b2, W2r,
                                               batch, pooled, gcnt, N);
    }

    // ---- classifier ----
    out_kernel<<<(G * NCLS + 255) / 256, 256, 0, stream>>>(pooled, gcnt, Wout, bout, out, G);
}

// Round 13
// 562.371 us; speedup vs baseline: 4.3862x; 4.3862x over previous
//
#include <hip/hip_runtime.h>

#define EMBED 32
#define HIDDEN 64
#define NCLS 10

// ============ CSR construction (round-6 proven) ============

__global__ void deg_kernel(const int* __restrict__ dst, int* __restrict__ deg, int nEdges) {
    int e = blockIdx.x * blockDim.x + threadIdx.x;
    if (e >= nEdges) return;
    atomicAdd(&deg[dst[e]], 1);
}

__global__ void block_sum_kernel(const int* __restrict__ deg, int* __restrict__ blockSums, int n) {
    __shared__ int s[256];
    int i = blockIdx.x * 256 + threadIdx.x;
    s[threadIdx.x] = (i < n) ? deg[i] : 0;
    __syncthreads();
    for (int off = 128; off > 0; off >>= 1) {
        if (threadIdx.x < off) s[threadIdx.x] += s[threadIdx.x + off];
        __syncthreads();
    }
    if (threadIdx.x == 0) blockSums[blockIdx.x] = s[0];
}

__global__ void scan_sums_kernel(int* blockSums, int nb) {
    if (blockIdx.x == 0 && threadIdx.x == 0) {
        int acc = 0;
        for (int i = 0; i < nb; ++i) { int v = blockSums[i]; blockSums[i] = acc; acc += v; }
    }
}

__global__ void scan_local_kernel(const int* __restrict__ deg, const int* __restrict__ blockSums,
                                  int* __restrict__ rowptr, int n) {
    __shared__ int s[256];
    int i = blockIdx.x * 256 + threadIdx.x;
    int v = (i < n) ? deg[i] : 0;
    s[threadIdx.x] = v;
    __syncthreads();
    for (int off = 1; off < 256; off <<= 1) {
        int t = (threadIdx.x >= off) ? s[threadIdx.x - off] : 0;
        __syncthreads();
        s[threadIdx.x] += t;
        __syncthreads();
    }
    if (i < n) rowptr[i] = blockSums[blockIdx.x] + s[threadIdx.x] - v;  // exclusive
}

__global__ void fill_kernel(const int* __restrict__ src, const int* __restrict__ dst,
                            const int* __restrict__ rowptr, int* __restrict__ cursor,
                            int* __restrict__ nbr, int nEdges) {
    int e = blockIdx.x * blockDim.x + threadIdx.x;
    if (e >= nEdges) return;
    int d = dst[e];
    int pos = atomicAdd(&cursor[d], 1);
    nbr[rowptr[d] + pos] = src[e];
}

// gcnt[g] = #nodes with batch==g via binary search (batch sorted) — round-10 proven
__global__ void gcnt_kernel(const int* __restrict__ batch, float* __restrict__ gcnt,
                            int nNodes, int nGraphs) {
    int g = blockIdx.x * blockDim.x + threadIdx.x;
    if (g >= nGraphs) return;
    int lo = 0, hi = nNodes;
    while (lo < hi) { int m = (lo + hi) >> 1; if (batch[m] < g) lo = m + 1; else hi = m; }
    int lo2 = lo, hi2 = nNodes;
    while (lo2 < hi2) { int m = (lo2 + hi2) >> 1; if (batch[m] <= g) lo2 = m + 1; else hi2 = m; }
    gcnt[g] = (float)(lo2 - lo);
}

// ============ Layer 1: 2 nodes/wave (one per 32-lane half), packed readlane GEMM ============
__launch_bounds__(512)
__global__ void layer1_fused(const int* __restrict__ nbr, const int* __restrict__ rowptr,
                             const int* __restrict__ deg, const int* __restrict__ node_ids,
                             const float* __restrict__ embed,
                             const float* __restrict__ W1l, const float* __restrict__ b1,
                             const float* __restrict__ W1r, float* __restrict__ h1, int nNodes) {
    __shared__ float sW[EMBED * 2 * HIDDEN];   // 16 KB, (Wl,Wr) interleaved pairs
    int tid = threadIdx.x;
    for (int i = tid; i < EMBED * HIDDEN; i += 512) {
        int k = i >> 6, c = i & 63;
        sW[k * 128 + 2 * c]     = W1l[i];
        sW[k * 128 + 2 * c + 1] = W1r[i];
    }
    __syncthreads();

    int wave = tid >> 6, lane = tid & 63;
    int half = lane >> 5, f = lane & 31;
    float bias = b1[lane];

    for (int p = blockIdx.x * 8 + wave; 2 * p < nNodes; p += gridDim.x * 8) {
        int n0 = 2 * p, n1 = 2 * p + 1;
        bool has1 = (n1 < nNodes);
        int n = half ? n1 : n0;                 // each half owns one node
        bool valid = half ? has1 : true;
        int dg = valid ? deg[n] : 0;
        int st = valid ? rowptr[n] : 0;

        // x packed: lanes 0..31 = x[n0][f], lanes 32..63 = x[n1][f]
        float xv = valid ? embed[(size_t)node_ids[n] * EMBED + f] : 0.f;

        // gather: each half sums its node's neighbors, unroll 4 -> 8 rows in flight per wave
        float s0 = 0.f, s1 = 0.f, s2 = 0.f, s3 = 0.f;
        int j = 0;
        for (; j + 3 < dg; j += 4) {
            int i0 = nbr[st + j], i1 = nbr[st + j + 1];
            int i2 = nbr[st + j + 2], i3 = nbr[st + j + 3];
            s0 += embed[(size_t)node_ids[i0] * EMBED + f];
            s1 += embed[(size_t)node_ids[i1] * EMBED + f];
            s2 += embed[(size_t)node_ids[i2] * EMBED + f];
            s3 += embed[(size_t)node_ids[i3] * EMBED + f];
        }
        for (; j < dg; ++j)
            s0 += embed[(size_t)node_ids[nbr[st + j]] * EMBED + f];
        float aggv = ((s0 + s1) + (s2 + s3)) / fmaxf((float)dg, 1.f);   // packed like xv

        // dual GEMM: out feature = lane; k from lane k (n0) and lane 32+k (n1)
        float acc0 = bias, acc1 = bias;
        #pragma unroll
        for (int k = 0; k < EMBED; ++k) {
            float2 w = *(const float2*)&sW[k * 128 + 2 * lane];
            acc0 += __shfl(aggv, k) * w.x + __shfl(xv, k) * w.y;
            acc1 += __shfl(aggv, EMBED + k) * w.x + __shfl(xv, EMBED + k) * w.y;
        }
        h1[(size_t)n0 * HIDDEN + lane] = fmaxf(acc0, 0.f);
        if (has1) h1[(size_t)n1 * HIDDEN + lane] = fmaxf(acc1, 0.f);
    }
}

// ============ Layer 2: 2 nodes/wave interleaved gather (8 rows in flight), dual GEMM, fused pool ============
__launch_bounds__(512)
__global__ void layer2_fused(const int* __restrict__ nbr, const int* __restrict__ rowptr,
                             const int* __restrict__ deg, const float* __restrict__ h1,
                             const float* __restrict__ W2l, const float* __restrict__ b2,
                             const float* __restrict__ W2r, const int* __restrict__ batch,
                             float* __restrict__ pooled, int nNodes) {
    __shared__ float sW[HIDDEN * 2 * HIDDEN];  // 32 KB, (Wl,Wr) interleaved pairs
    int tid = threadIdx.x;
    for (int i = tid; i < HIDDEN * HIDDEN; i += 512) {
        int k = i >> 6, c = i & 63;
        sW[k * 128 + 2 * c]     = W2l[i];
        sW[k * 128 + 2 * c + 1] = W2r[i];
    }
    __syncthreads();

    int wave = tid >> 6, lane = tid & 63;
    float bias = b2[lane];

    for (int p = blockIdx.x * 8 + wave; 2 * p < nNodes; p += gridDim.x * 8) {
        int n0 = 2 * p, n1 = 2 * p + 1;
        bool has1 = (n1 < nNodes);
        int dg0 = deg[n0], st0 = rowptr[n0];
        int dg1 = has1 ? deg[n1] : 0;
        int st1 = has1 ? rowptr[n1] : 0;

        float xv0 = h1[(size_t)n0 * HIDDEN + lane];
        float xv1 = has1 ? h1[(size_t)n1 * HIDDEN + lane] : 0.f;

        // interleaved gather: both nodes' unroll-4 groups -> 8 independent rows in flight
        float s00 = 0.f, s01 = 0.f, s02 = 0.f, s03 = 0.f;
        float s10 = 0.f, s11 = 0.f, s12 = 0.f, s13 = 0.f;
        int m = dg0 < dg1 ? dg0 : dg1;
        int j = 0;
        for (; j + 3 < m; j += 4) {
            int a0 = nbr[st0 + j], a1 = nbr[st0 + j + 1];
            int a2 = nbr[st0 + j + 2], a3 = nbr[st0 + j + 3];
            int c0 = nbr[st1 + j], c1 = nbr[st1 + j + 1];
            int c2 = nbr[st1 + j + 2], c3 = nbr[st1 + j + 3];
            s00 += h1[(size_t)a0 * HIDDEN + lane];
            s01 += h1[(size_t)a1 * HIDDEN + lane];
            s02 += h1[(size_t)a2 * HIDDEN + lane];
            s03 += h1[(size_t)a3 * HIDDEN + lane];
            s10 += h1[(size_t)c0 * HIDDEN + lane];
            s11 += h1[(size_t)c1 * HIDDEN + lane];
            s12 += h1[(size_t)c2 * HIDDEN + lane];
            s13 += h1[(size_t)c3 * HIDDEN + lane];
        }
        // tails (wave-uniform trip counts, unroll 2)
        int t = j;
        for (; t + 1 < dg0; t += 2) {
            int a0 = nbr[st0 + t], a1 = nbr[st0 + t + 1];
            s00 += h1[(size_t)a0 * HIDDEN + lane];
            s01 += h1[(size_t)a1 * HIDDEN + lane];
        }
        if (t < dg0) s00 += h1[(size_t)nbr[st0 + t] * HIDDEN + lane];
        t = j;
        for (; t + 1 < dg1; t += 2) {
            int c0 = nbr[st1 + t], c1 = nbr[st1 + t + 1];
            s10 += h1[(size_t)c0 * HIDDEN + lane];
            s11 += h1[(size_t)c1 * HIDDEN + lane];
        }
        if (t < dg1) s10 += h1[(size_t)nbr[st1 + t] * HIDDEN + lane];

        float ag0 = ((s00 + s01) + (s02 + s03)) / fmaxf((float)dg0, 1.f);
        float ag1 = ((s10 + s11) + (s12 + s13)) / fmaxf((float)dg1, 1.f);

        // dual GEMM, shared weight reads (one ds_read_b64 per k for both nodes)
        float acc0 = bias, acc1 = bias;
        #pragma unroll 16
        for (int k = 0; k < HIDDEN; ++k) {
            float2 w = *(const float2*)&sW[k * 128 + 2 * lane];
            acc0 += __shfl(ag0, k) * w.x + __shfl(xv0, k) * w.y;
            acc1 += __shfl(ag1, k) * w.x + __shfl(xv1, k) * w.y;
        }
        float a0 = fmaxf(acc0, 0.f);
        int g0 = batch[n0];
        if (has1) {
            float a1 = fmaxf(acc1, 0.f);
            int g1 = batch[n1];
            if (g0 == g1) {
                atomicAdd(&pooled[(size_t)g0 * HIDDEN + lane], a0 + a1);
            } else {
                atomicAdd(&pooled[(size_t)g0 * HIDDEN + lane], a0);
                atomicAdd(&pooled[(size_t)g1 * HIDDEN + lane], a1);
            }
        } else {
            atomicAdd(&pooled[(size_t)g0 * HIDDEN + lane], a0);
        }
    }
}

// ============ classifier ============
__global__ void out_kernel(const float* __restrict__ pooled, const float* __restrict__ gcnt,
                           const float* __restrict__ Wout, const float* __restrict__ bout,
                           float* __restrict__ out, int nGraphs) {
    int i = blockIdx.x * blockDim.x + threadIdx.x;
    if (i >= nGraphs * NCLS) return;
    int g = i / NCLS;
    int c = i % NCLS;
    float inv = 1.0f / fmaxf(gcnt[g], 1.0f);
    float acc = bout[c];
    #pragma unroll
    for (int k = 0; k < HIDDEN; ++k)
        acc += pooled[(size_t)g * HIDDEN + k] * inv * Wout[k * NCLS + c];
    out[i] = acc;
}

extern "C" void kernel_launch(void* const* d_in, const int* in_sizes, int n_in,
                              void* d_out, int out_size, void* d_ws, size_t ws_size,
                              hipStream_t stream) {
    const int*   node_ids = (const int*)d_in[0];
    const int*   src      = (const int*)d_in[1];
    const int*   dst      = (const int*)d_in[2];
    const int*   batch    = (const int*)d_in[3];
    const float* embed    = (const float*)d_in[4];
    const float* W1l      = (const float*)d_in[5];
    const float* b1       = (const float*)d_in[6];
    const float* W1r      = (const float*)d_in[7];
    const float* W2l      = (const float*)d_in[8];
    const float* b2       = (const float*)d_in[9];
    const float* W2r      = (const float*)d_in[10];
    const float* Wout     = (const float*)d_in[11];
    const float* bout     = (const float*)d_in[12];

    const int N = in_sizes[0];          // 100000
    const int E = in_sizes[1];          // 1200000
    const int G = out_size / NCLS;      // 1024
    const int NB = (N + 255) / 256;

    // ws: deg[N] | rowptr[N] | cursor[N] | blockSums(pad) | nbr(padE) (ints)
    //     h1[N*64] | pooled[G*64] | gcnt[padG] (floats)
    int* deg       = (int*)d_ws;
    int* rowptr    = deg + N;
    int* cursor    = rowptr + N;
    int* blockSums = cursor + N;
    int* nbr       = blockSums + ((NB + 63) & ~63);
    float* h1      = (float*)(nbr + ((E + 63) & ~63));
    float* pooled  = h1 + (size_t)N * HIDDEN;
    float* gcnt    = pooled + (size_t)G * HIDDEN;

    float* out = (float*)d_out;

    // ---- CSR build ----
    hipMemsetAsync(deg, 0, (size_t)N * sizeof(int), stream);
    hipMemsetAsync(cursor, 0, (size_t)N * sizeof(int), stream);
    deg_kernel<<<(E + 255) / 256, 256, 0, stream>>>(dst, deg, E);
    block_sum_kernel<<<NB, 256, 0, stream>>>(deg, blockSums, N);
    scan_sums_kernel<<<1, 1, 0, stream>>>(blockSums, NB);
    scan_local_kernel<<<NB, 256, 0, stream>>>(deg, blockSums, rowptr, N);
    fill_kernel<<<(E + 255) / 256, 256, 0, stream>>>(src, dst, rowptr, cursor, nbr, E);

    gcnt_kernel<<<(G + 255) / 256, 256, 0, stream>>>(batch, gcnt, N, G);
    hipMemsetAsync(pooled, 0, (size_t)G * HIDDEN * sizeof(float), stream);

    // ---- layer 1 ----
    layer1_fused<<<1024, 512, 0, stream>>>(nbr, rowptr, deg, node_ids, embed,
                                           W1l, b1, W1r, h1, N);

    // ---- layer 2 + pool ----
    layer2_fused<<<1024, 512, 0, stream>>>(nbr, rowptr, deg, h1, W2l, b2, W2r,
                                           batch, pooled, N);

    // ---- classifier ----
    out_kernel<<<(G * NCLS + 255) / 256, 256, 0, stream>>>(pooled, gcnt, Wout, bout, out, G);
}